// Round 1
// baseline (4896.650 us; speedup 1.0000x reference)
//
#include <hip/hip_runtime.h>

#define JITF 1e-4f
#define LOG2PIF 1.8378770664093454f

// problem sizes (fixed): D=32, dy=32, M=128, N=128, B=8, T=48
// ws offsets (in floats)
#define OW_TAPER 0
#define OW_ZS    1024
#define OW_ZS2   132096
#define OW_KINV  136192
#define OW_U     660480
#define OW_A     1184768
#define OW_XW    1709056
#define OW_XM    1741824
#define OW_LLP   1742080
#define OW_KLD   1742464
// out offsets
#define OFM 1048577
#define OFV 1060865

// ---------------- taper + zs + zs2 ----------------
__global__ void k_prep(const float* __restrict__ ips, const float* __restrict__ ls,
                       float* __restrict__ zs, float* __restrict__ zs2, float* __restrict__ taper)
{
  int gid = blockIdx.x * 256 + threadIdx.x;
  if (gid < 4096) {
    int d = gid >> 7, m = gid & 127;
    float invl = 1.0f / ls[d];
    float s2 = 0.f;
#pragma unroll
    for (int k = 0; k < 32; k++) {
      float v = ips[(d * 128 + m) * 32 + k] * invl;
      zs[(d * 128 + m) * 32 + k] = v;
      s2 = fmaf(v, v, s2);
    }
    zs2[d * 128 + m] = s2;
  } else if (gid < 5120) {
    int e = gid - 4096;
    int i = e >> 5, j = e & 31;
    int ad = i - j; if (ad < 0) ad = -ad;
    int dist = (ad < 32 - ad) ? ad : (32 - ad);
    double z = (double)dist / 5.0;
    double z2 = z * z, z3 = z2 * z, z4 = z3 * z, z5 = z4 * z;
    double g;
    if (z < 1.0) g = 1.0 - (5.0 / 3.0) * z2 + (5.0 / 8.0) * z3 + 0.5 * z4 - 0.25 * z5;
    else if (z < 2.0) {
      double zsafe = z > 1e-12 ? z : 1e-12;
      g = 4.0 - 5.0 * z + (5.0 / 3.0) * z2 + (5.0 / 8.0) * z3 - 0.5 * z4 + (1.0 / 12.0) * z5
          - 2.0 / (3.0 * zsafe);
    } else g = 0.0;
    taper[e] = (float)g;
  }
}

// ---------------- Kzz -> chol -> Linv (upper) -> Kinv + KL partials ----------------
// kld layout: [0..31]=sum log Ldiag, [32..63]=trace_d, [64..95]=mah_d, [96..127]=sum log|qL diag|
__global__ __launch_bounds__(256) void k_cholinv(
    const float* __restrict__ zs, const float* __restrict__ zs2, const float* __restrict__ osc,
    const float* __restrict__ qL, const float* __restrict__ qmu,
    float* __restrict__ Kinv, float* __restrict__ kld)
{
  __shared__ float As[128][129];
  __shared__ float zss[128][33];
  __shared__ float Ldi[128];
  __shared__ float red[256];
  const int d = blockIdx.x, tid = threadIdx.x;

  for (int l = tid; l < 4096; l += 256) zss[l >> 5][l & 31] = zs[d * 4096 + l];
  __syncthreads();
  const float oscd = osc[d];
  for (int e = tid; e < 16384; e += 256) {
    int i = e >> 7, j = e & 127;
    float dot = 0.f;
#pragma unroll
    for (int k = 0; k < 32; k++) dot = fmaf(zss[i][k], zss[j][k], dot);
    float d2 = fmaxf(zs2[d * 128 + i] + zs2[d * 128 + j] - 2.f * dot, 0.f);
    As[i][j] = oscd * expf(-0.5f * d2) + (i == j ? JITF : 0.f);
  }
  __syncthreads();

  // Cholesky (lower in As), thread = row, right-looking
  for (int j = 0; j < 128; j++) {
    if (tid == j) As[j][j] = sqrtf(As[j][j]);
    __syncthreads();
    if (tid < 128 && tid > j) As[tid][j] /= As[j][j];
    __syncthreads();
    if (tid < 128 && tid > j) {
      float lij = As[tid][j];
      for (int k = j + 1; k <= tid; k++) As[tid][k] = fmaf(-lij, As[k][j], As[tid][k]);
    }
    __syncthreads();
  }

  if (tid == 0) {
    float s = 0.f;
    for (int j = 0; j < 128; j++) s += logf(As[j][j]);
    kld[d] = s;
    float s2 = 0.f;
    for (int i = 0; i < 128; i++) s2 += logf(fabsf(qL[(d * 128 + i) * 128 + i]));
    kld[96 + d] = s2;
  }

  // triangular inverse: thread = column j; Linv[i][j] stored at As[j][i] (upper), diag in Ldi
  if (tid < 128) {
    int j = tid;
    float dj = 1.0f / As[j][j];
    Ldi[j] = dj;
    for (int i = j + 1; i < 128; i++) {
      float s = As[i][j] * dj;                       // k=j term: L[i][j]*Linv[j][j]
      for (int k = j + 1; k < i; k++) s = fmaf(As[i][k], As[j][k], s); // L[i][k]*Linv[k][j]
      As[j][i] = -s / As[i][i];
    }
  }
  __syncthreads();

  // Kinv = Linv^T Linv
  for (int e = tid; e < 16384; e += 256) {
    int i = e >> 7, j = e & 127;
    int k0 = i > j ? i : j;
    float a0 = (k0 == i) ? Ldi[i] : As[i][k0];
    float b0 = (k0 == j) ? Ldi[j] : As[j][k0];
    float s0 = a0 * b0, s1 = 0.f;
    int k = k0 + 1;
    for (; k + 1 < 128; k += 2) {
      s0 = fmaf(As[i][k], As[j][k], s0);
      s1 = fmaf(As[i][k + 1], As[j][k + 1], s1);
    }
    for (; k < 128; k++) s0 = fmaf(As[i][k], As[j][k], s0);
    Kinv[d * 16384 + e] = s0 + s1;
  }

  // trace_d = ||Linv qL||_F^2
  float tacc = 0.f;
  for (int e = tid; e < 16384; e += 256) {
    int i = e >> 7, k = e & 127;
    if (k <= i) {
      float s = Ldi[i] * qL[(d * 128 + i) * 128 + k];  // m=i term
      for (int m = k; m < i; m++) s = fmaf(As[m][i], qL[(d * 128 + m) * 128 + k], s);
      tacc = fmaf(s, s, tacc);
    }
  }
  // mah_d = ||Linv qmu||^2
  float macc = 0.f;
  if (tid < 128) {
    int i = tid;
    float s = Ldi[i] * qmu[d * 128 + i];
    for (int m = 0; m < i; m++) s = fmaf(As[m][i], qmu[d * 128 + m], s);
    macc = s * s;
  }
  __syncthreads();
  red[tid] = tacc; __syncthreads();
  for (int s = 128; s > 0; s >>= 1) { if (tid < s) red[tid] += red[tid + s]; __syncthreads(); }
  if (tid == 0) kld[32 + d] = red[0];
  __syncthreads();
  red[tid] = macc; __syncthreads();
  for (int s = 128; s > 0; s >>= 1) { if (tid < s) red[tid] += red[tid + s]; __syncthreads(); }
  if (tid == 0) kld[64 + d] = red[0];
}

// ---------------- U = q_mu + q_L @ eps_u ----------------
__global__ __launch_bounds__(128) void k_U(
    const float* __restrict__ qL, const float* __restrict__ qmu, const float* __restrict__ eu,
    float* __restrict__ U)
{
  __shared__ float qLs[128][129];
  __shared__ float eus[128];
  const int d = blockIdx.x >> 2, nc = blockIdx.x & 3, tid = threadIdx.x;
  for (int l = tid; l < 16384; l += 128) qLs[l >> 7][l & 127] = qL[d * 16384 + l];
  __syncthreads();
  const float qm = qmu[d * 128 + tid];
  for (int nn = 0; nn < 32; nn++) {
    int n = nc * 32 + nn;
    eus[tid] = eu[(n * 32 + d) * 128 + tid];
    __syncthreads();
    int kmax = tid + 1;
    int k4 = kmax & ~3;
    float s0 = qm, s1 = 0.f, s2 = 0.f, s3 = 0.f;
    int k = 0;
    for (; k < k4; k += 4) {
      s0 = fmaf(qLs[tid][k], eus[k], s0);
      s1 = fmaf(qLs[tid][k + 1], eus[k + 1], s1);
      s2 = fmaf(qLs[tid][k + 2], eus[k + 2], s2);
      s3 = fmaf(qLs[tid][k + 3], eus[k + 3], s3);
    }
    for (; k < kmax; k++) s0 = fmaf(qLs[tid][k], eus[k], s0);
    U[(n * 32 + d) * 128 + tid] = (s0 + s1) + (s2 + s3);
    __syncthreads();
  }
}

// ---------------- A = Kinv @ U ----------------
__global__ __launch_bounds__(256) void k_A2(
    const float* __restrict__ Kinv, const float* __restrict__ U, float* __restrict__ A)
{
  __shared__ float Kis[128][129];
  __shared__ float Us[32][129];
  const int d = blockIdx.x >> 2, nc = blockIdx.x & 3, tid = threadIdx.x;
  const int n0 = nc * 32;
  for (int l = tid; l < 16384; l += 256) Kis[l >> 7][l & 127] = Kinv[d * 16384 + l];
  for (int l = tid; l < 4096; l += 256) Us[l >> 7][l & 127] = U[((n0 + (l >> 7)) * 32 + d) * 128 + (l & 127)];
  __syncthreads();
  for (int e = tid; e < 4096; e += 256) {
    int nl = e >> 7, m = e & 127;
    float s0 = 0.f, s1 = 0.f, s2 = 0.f, s3 = 0.f;
    for (int k = 0; k < 128; k += 4) {
      s0 = fmaf(Kis[m][k], Us[nl][k], s0);
      s1 = fmaf(Kis[m][k + 1], Us[nl][k + 1], s1);
      s2 = fmaf(Kis[m][k + 2], Us[nl][k + 2], s2);
      s3 = fmaf(Kis[m][k + 3], Us[nl][k + 3], s3);
    }
    A[((n0 + nl) * 32 + d) * 128 + m] = (s0 + s1) + (s2 + s3);
  }
}

// ---------------- t = 0: full per-(n,d) GP predict ----------------
__global__ __launch_bounds__(128) void k_t0gp(
    const float* __restrict__ x0, const float* __restrict__ ls, const float* __restrict__ osc,
    const float* __restrict__ qn, const float* __restrict__ zs, const float* __restrict__ zs2,
    const float* __restrict__ Kinv, const float* __restrict__ A,
    const float* __restrict__ ef, const float* __restrict__ eq, float* __restrict__ Xw)
{
  __shared__ float zss[128][33];
  __shared__ float xqs[8][33];
  __shared__ float xq2s[8];
  __shared__ float Kxzs[8][132];
  __shared__ float T1s[8][132];
  __shared__ float covs[8][9];
  __shared__ float Lc[8][9];
  __shared__ float Arow[128];
  const int n = blockIdx.x >> 5, d = blockIdx.x & 31, tid = threadIdx.x;
  const float invl = 1.0f / ls[d], oscd = osc[d];
  for (int l = tid; l < 4096; l += 128) zss[l >> 5][l & 31] = zs[d * 4096 + l];
  for (int l = tid; l < 256; l += 128) {
    int b = l >> 5, k = l & 31;
    xqs[b][k] = x0[((n * 32 + d) * 8 + b) * 32 + k] * invl;
  }
  Arow[tid] = A[(n * 32 + d) * 128 + tid];
  __syncthreads();
  if (tid < 8) {
    float s = 0.f;
#pragma unroll
    for (int k = 0; k < 32; k++) { float v = xqs[tid][k]; s = fmaf(v, v, s); }
    xq2s[tid] = s;
  }
  __syncthreads();
  { // Kxz
    float z2m = zs2[d * 128 + tid];
#pragma unroll
    for (int b = 0; b < 8; b++) {
      float dot = 0.f;
#pragma unroll
      for (int k = 0; k < 32; k++) dot = fmaf(xqs[b][k], zss[tid][k], dot);
      Kxzs[b][tid] = oscd * expf(-0.5f * fmaxf(xq2s[b] + z2m - 2.f * dot, 0.f));
    }
  }
  __syncthreads();
  { // T1 = Kxz @ Kinv[d]
    float a[8] = {0.f, 0.f, 0.f, 0.f, 0.f, 0.f, 0.f, 0.f};
    const float* kp = Kinv + d * 16384 + tid;
    for (int mm = 0; mm < 128; mm++) {
      float kv = kp[mm * 128];
#pragma unroll
      for (int b = 0; b < 8; b++) a[b] = fmaf(Kxzs[b][mm], kv, a[b]);
    }
#pragma unroll
    for (int b = 0; b < 8; b++) T1s[b][tid] = a[b];
  }
  __syncthreads();
  if (tid < 64) { // cov
    int b = tid >> 3, c = tid & 7;
    float dot = 0.f;
#pragma unroll
    for (int k = 0; k < 32; k++) dot = fmaf(xqs[b][k], xqs[c][k], dot);
    float kxx = oscd * expf(-0.5f * fmaxf(xq2s[b] + xq2s[c] - 2.f * dot, 0.f));
    float s0 = 0.f, s1 = 0.f;
    for (int m = 0; m < 128; m += 2) {
      s0 = fmaf(T1s[b][m], Kxzs[c][m], s0);
      s1 = fmaf(T1s[b][m + 1], Kxzs[c][m + 1], s1);
    }
    covs[b][c] = kxx - (s0 + s1) + (b == c ? JITF : 0.f);
  }
  __syncthreads();
  if (tid == 0) { // chol 8x8
    for (int a = 0; a < 8; a++) {
      float s = covs[a][a];
      for (int k = 0; k < a; k++) s -= Lc[a][k] * Lc[a][k];
      float la = sqrtf(s);
      Lc[a][a] = la;
      for (int i = a + 1; i < 8; i++) {
        float s2 = covs[i][a];
        for (int k = 0; k < a; k++) s2 -= Lc[i][k] * Lc[a][k];
        Lc[i][a] = s2 / la;
      }
      for (int c = a + 1; c < 8; c++) Lc[a][c] = 0.f;
    }
  }
  __syncthreads();
  if (tid < 8) {
    int b = tid;
    float m0 = 0.f, m1 = 0.f;
    for (int m = 0; m < 128; m += 2) {
      m0 = fmaf(Kxzs[b][m], Arow[m], m0);
      m1 = fmaf(Kxzs[b][m + 1], Arow[m + 1], m1);
    }
    float f = m0 + m1;
#pragma unroll
    for (int c = 0; c < 8; c++) f = fmaf(Lc[b][c], ef[(n * 32 + d) * 8 + c], f);
    float X = f + eq[(b * 128 + n) * 32 + d] * sqrtf(qn[d]);
    Xw[(d * 8 + b) * 128 + n] = X;
  }
}

// ---------------- t >= 1: shared GP + ensemble construct ----------------
__global__ __launch_bounds__(256) void k_stepAB(
    int t, const float* __restrict__ xm,
    const float* __restrict__ ls, const float* __restrict__ osc, const float* __restrict__ qn,
    const float* __restrict__ zs, const float* __restrict__ zs2,
    const float* __restrict__ Kinv, const float* __restrict__ A,
    const float* __restrict__ ef, const float* __restrict__ eq, float* __restrict__ Xw)
{
  __shared__ float zss[128][33];
  __shared__ float zs2s[128];
  __shared__ float xqs[8][33];
  __shared__ float xq2s[8];
  __shared__ float Kxzs[8][132];
  __shared__ float T1s[8][132];
  __shared__ float covs[8][9];
  __shared__ float Lc[8][9];
  __shared__ float As_t[32][129];
  __shared__ float efs[32][8];
  const int d = blockIdx.x, tid = threadIdx.x;
  const float invl = 1.0f / ls[d], oscd = osc[d];
  for (int l = tid; l < 4096; l += 256) zss[l >> 5][l & 31] = zs[d * 4096 + l];
  if (tid < 128) zs2s[tid] = zs2[d * 128 + tid];
  { int b = tid >> 5, k = tid & 31; xqs[b][k] = xm[b * 32 + k] * invl; }
  __syncthreads();
  if (tid < 8) {
    float s = 0.f;
#pragma unroll
    for (int k = 0; k < 32; k++) { float v = xqs[tid][k]; s = fmaf(v, v, s); }
    xq2s[tid] = s;
  }
  __syncthreads();
  for (int e = tid; e < 1024; e += 256) { // Kxz0
    int b = e >> 7, m = e & 127;
    float dot = 0.f;
#pragma unroll
    for (int k = 0; k < 32; k++) dot = fmaf(xqs[b][k], zss[m][k], dot);
    Kxzs[b][m] = oscd * expf(-0.5f * fmaxf(xq2s[b] + zs2s[m] - 2.f * dot, 0.f));
  }
  __syncthreads();
  { // T1 = Kxz0 @ Kinv[d]
    int m = tid & 127, half = tid >> 7;
    float a0 = 0.f, a1 = 0.f, a2 = 0.f, a3 = 0.f;
    const float* kp = Kinv + d * 16384 + m;
    for (int mm = 0; mm < 128; mm++) {
      float kv = kp[mm * 128];
      a0 = fmaf(Kxzs[half + 0][mm], kv, a0);
      a1 = fmaf(Kxzs[half + 2][mm], kv, a1);
      a2 = fmaf(Kxzs[half + 4][mm], kv, a2);
      a3 = fmaf(Kxzs[half + 6][mm], kv, a3);
    }
    T1s[half + 0][m] = a0; T1s[half + 2][m] = a1; T1s[half + 4][m] = a2; T1s[half + 6][m] = a3;
  }
  __syncthreads();
  if (tid < 64) { // cov
    int b = tid >> 3, c = tid & 7;
    float dot = 0.f;
#pragma unroll
    for (int k = 0; k < 32; k++) dot = fmaf(xqs[b][k], xqs[c][k], dot);
    float kxx = oscd * expf(-0.5f * fmaxf(xq2s[b] + xq2s[c] - 2.f * dot, 0.f));
    float s0 = 0.f, s1 = 0.f;
    for (int m = 0; m < 128; m += 2) {
      s0 = fmaf(T1s[b][m], Kxzs[c][m], s0);
      s1 = fmaf(T1s[b][m + 1], Kxzs[c][m + 1], s1);
    }
    covs[b][c] = kxx - (s0 + s1) + (b == c ? JITF : 0.f);
  }
  __syncthreads();
  if (tid == 0) { // chol 8x8
    for (int a = 0; a < 8; a++) {
      float s = covs[a][a];
      for (int k = 0; k < a; k++) s -= Lc[a][k] * Lc[a][k];
      float la = sqrtf(s);
      Lc[a][a] = la;
      for (int i = a + 1; i < 8; i++) {
        float s2 = covs[i][a];
        for (int k = 0; k < a; k++) s2 -= Lc[i][k] * Lc[a][k];
        Lc[i][a] = s2 / la;
      }
      for (int c = a + 1; c < 8; c++) Lc[a][c] = 0.f;
    }
  }
  __syncthreads();
  const float qsd = sqrtf(qn[d]);
  for (int n0 = 0; n0 < 128; n0 += 32) {
    for (int l = tid; l < 4096; l += 256) {
      int nl = l >> 7, mk = l & 127;
      As_t[nl][mk] = A[((n0 + nl) * 32 + d) * 128 + mk];
    }
    { int nl = tid >> 3, c = tid & 7;
      efs[nl][c] = ef[((t * 128 + n0 + nl) * 32 + d) * 8 + c]; }
    __syncthreads();
    {
      int b = tid & 7, nl = tid >> 3;
      float m0 = 0.f, m1 = 0.f;
      for (int m = 0; m < 128; m += 2) {
        m0 = fmaf(Kxzs[b][m], As_t[nl][m], m0);
        m1 = fmaf(Kxzs[b][m + 1], As_t[nl][m + 1], m1);
      }
      float f = m0 + m1;
#pragma unroll
      for (int c = 0; c < 8; c++) f = fmaf(Lc[b][c], efs[nl][c], f);
      float X = f + eq[((t * 8 + b) * 128 + n0 + nl) * 32 + d] * qsd;
      Xw[(d * 8 + b) * 128 + (n0 + nl)] = X;
    }
    __syncthreads();
  }
}

// ---------------- moments + Kalman update (per b) ----------------
__global__ __launch_bounds__(256) void k_stepC(
    int t, const float* __restrict__ Xw, const float* __restrict__ taper,
    const float* __restrict__ H, const float* __restrict__ rn,
    const float* __restrict__ y, const float* __restrict__ er,
    float* __restrict__ out, float* __restrict__ xm, float* __restrict__ llp)
{
  __shared__ float Xs[128][33];
  __shared__ float Hs[32][33];
  __shared__ float Ps[32][33];
  __shared__ float HPs[32][33];
  __shared__ float Ss[32][33];
  __shared__ float Lss[32][33];
  __shared__ float Lis[32][33];
  __shared__ float Sis[32][33];
  __shared__ float Ks[32][33];
  __shared__ float Xms[32], mers[32], resid[32], alph[32], mi[32];
  const int b = blockIdx.x, tid = threadIdx.x;
  for (int l = tid; l < 4096; l += 256) {
    int dd = l >> 7, n = l & 127;
    Xs[n][dd] = Xw[(dd * 8 + b) * 128 + n];
  }
  for (int l = tid; l < 1024; l += 256) Hs[l >> 5][l & 31] = H[l];
  __syncthreads();
  if (tid < 32) {
    float s = 0.f;
    for (int n = 0; n < 128; n++) s += Xs[n][tid];
    Xms[tid] = s * (1.0f / 128.0f);
  } else if (tid < 64) {
    int j = tid - 32;
    float s = 0.f;
    for (int n = 0; n < 128; n++) s += er[((t * 8 + b) * 128 + n) * 32 + j];
    mers[j] = s * (1.0f / 128.0f);
  }
  __syncthreads();
  for (int e = tid; e < 1024; e += 256) { // P
    int i = e >> 5, j = e & 31;
    float xi = Xms[i], xj = Xms[j];
    float s0 = 0.f, s1 = 0.f;
    for (int n = 0; n < 128; n += 2) {
      s0 = fmaf(Xs[n][i] - xi, Xs[n][j] - xj, s0);
      s1 = fmaf(Xs[n + 1][i] - xi, Xs[n + 1][j] - xj, s1);
    }
    Ps[i][j] = taper[e] * (s0 + s1) * (1.0f / 127.0f);
  }
  __syncthreads();
  for (int e = tid; e < 1024; e += 256) { // HP
    int j = e >> 5, i = e & 31;
    float s = 0.f;
#pragma unroll
    for (int k = 0; k < 32; k++) s = fmaf(Hs[j][k], Ps[k][i], s);
    HPs[j][i] = s;
  }
  __syncthreads();
  for (int e = tid; e < 1024; e += 256) { // S
    int j = e >> 5, l = e & 31;
    float s = 0.f;
#pragma unroll
    for (int k = 0; k < 32; k++) s = fmaf(HPs[j][k], Hs[l][k], s);
    Ss[j][l] = s + (j == l ? rn[j] : 0.f);
  }
  __syncthreads();
  for (int j = 0; j < 32; j++) { // chol S, left-looking
    float s = 0.f;
    if (tid < 32 && tid >= j) {
      s = Ss[tid][j];
      for (int k = 0; k < j; k++) s = fmaf(-Lss[tid][k], Lss[j][k], s);
      if (tid == j) Lss[j][j] = sqrtf(s);
    }
    __syncthreads();
    if (tid < 32 && tid > j) Lss[tid][j] = s / Lss[j][j];
    __syncthreads();
  }
  if (tid < 32) { // Linv
    int j = tid;
    Lis[j][j] = 1.0f / Lss[j][j];
    for (int i = j + 1; i < 32; i++) {
      float s = 0.f;
      for (int k = j; k < i; k++) s = fmaf(Lss[i][k], Lis[k][j], s);
      Lis[i][j] = -s / Lss[i][i];
    }
  }
  __syncthreads();
  for (int e = tid; e < 1024; e += 256) { // Sinv
    int i = e >> 5, j = e & 31;
    int k0 = i > j ? i : j;
    float s = 0.f;
    for (int k = k0; k < 32; k++) s = fmaf(Lis[k][i], Lis[k][j], s);
    Sis[i][j] = s;
  }
  __syncthreads();
  if (tid < 32) {
    float s = 0.f;
#pragma unroll
    for (int i = 0; i < 32; i++) s = fmaf(Hs[tid][i], Xms[i], s);
    resid[tid] = y[(b * 48 + t) * 32 + tid] - s;
  }
  __syncthreads();
  if (tid < 32) {
    float s = 0.f;
#pragma unroll
    for (int k = 0; k < 32; k++) s = fmaf(Sis[tid][k], resid[k], s);
    alph[tid] = s;
    mi[tid] = resid[tid] + mers[tid] * sqrtf(rn[tid]);
  }
  __syncthreads();
  if (tid == 0) {
    float quad = 0.f, ld = 0.f;
    for (int j = 0; j < 32; j++) { quad += resid[j] * alph[j]; ld += logf(Lss[j][j]); }
    llp[t * 8 + b] = -0.5f * (32.0f * LOG2PIF + 2.0f * ld + quad);
  }
  for (int e = tid; e < 1024; e += 256) { // K = PHt @ Sinv
    int i = e >> 5, j = e & 31;
    float s = 0.f;
#pragma unroll
    for (int k = 0; k < 32; k++) s = fmaf(HPs[k][i], Sis[k][j], s);
    Ks[i][j] = s;
  }
  __syncthreads();
  if (tid < 32) {
    int i = tid;
    float xs = 0.f, fv = 0.f;
#pragma unroll
    for (int j = 0; j < 32; j++) {
      xs = fmaf(Ks[i][j], mi[j], xs);
      fv = fmaf(Ks[i][j], HPs[j][i], fv);
    }
    float xmp = Xms[i] + xs;
    out[OFM + (b * 48 + t) * 32 + i] = xmp;
    out[OFV + (b * 48 + t) * 32 + i] = Ps[i][i] - fv;
    xm[b * 32 + i] = xmp;
  }
}

// ---------------- final reductions ----------------
__global__ void k_elbo(const float* __restrict__ llp, const float* __restrict__ kld,
                       float* __restrict__ out)
{
  if (blockIdx.x == 0 && threadIdx.x == 0) {
    double ll = 0.0;
    for (int i = 0; i < 384; i++) ll += (double)llp[i];
    double ldK = 0.0, tr = 0.0, mah = 0.0, ldS = 0.0;
    for (int d = 0; d < 32; d++) {
      ldK += (double)kld[d];
      tr  += (double)kld[32 + d];
      mah += (double)kld[64 + d];
      ldS += (double)kld[96 + d];
    }
    double kl = 0.5 * (tr + mah - 4096.0 + 2.0 * ldK - 2.0 * ldS);
    out[0] = (float)(ll - kl / 100000.0);
  }
}

__global__ void k_xfinal(const float* __restrict__ xm, float* __restrict__ out)
{
  int idx = blockIdx.x * 256 + threadIdx.x;
  int k = idx & 31;
  int b = (idx >> 5) & 7;
  out[idx] = xm[b * 32 + k];
}

extern "C" void kernel_launch(void* const* d_in, const int* in_sizes, int n_in,
                              void* d_out, int out_size, void* d_ws, size_t ws_size,
                              hipStream_t stream) {
  const float* ips = (const float*)d_in[0];
  const float* H   = (const float*)d_in[1];
  const float* ls  = (const float*)d_in[2];
  const float* osc = (const float*)d_in[3];
  const float* qmu = (const float*)d_in[4];
  const float* qL  = (const float*)d_in[5];
  const float* qn  = (const float*)d_in[6];
  const float* rn  = (const float*)d_in[7];
  const float* x0  = (const float*)d_in[8];
  const float* y   = (const float*)d_in[9];
  const float* eu  = (const float*)d_in[10];
  const float* ef  = (const float*)d_in[11];
  const float* eq  = (const float*)d_in[12];
  const float* er  = (const float*)d_in[13];
  float* out = (float*)d_out;
  float* ws  = (float*)d_ws;

  float* w_taper = ws + OW_TAPER;
  float* w_zs    = ws + OW_ZS;
  float* w_zs2   = ws + OW_ZS2;
  float* w_kinv  = ws + OW_KINV;
  float* w_U     = ws + OW_U;
  float* w_A     = ws + OW_A;
  float* w_Xw    = ws + OW_XW;
  float* w_xm    = ws + OW_XM;
  float* w_llp   = ws + OW_LLP;
  float* w_kld   = ws + OW_KLD;

  k_prep<<<20, 256, 0, stream>>>(ips, ls, w_zs, w_zs2, w_taper);
  k_cholinv<<<32, 256, 0, stream>>>(w_zs, w_zs2, osc, qL, qmu, w_kinv, w_kld);
  k_U<<<128, 128, 0, stream>>>(qL, qmu, eu, w_U);
  k_A2<<<128, 256, 0, stream>>>(w_kinv, w_U, w_A);
  k_t0gp<<<4096, 128, 0, stream>>>(x0, ls, osc, qn, w_zs, w_zs2, w_kinv, w_A, ef, eq, w_Xw);
  k_stepC<<<8, 256, 0, stream>>>(0, w_Xw, w_taper, H, rn, y, er, out, w_xm, w_llp);
  for (int t = 1; t < 48; t++) {
    k_stepAB<<<32, 256, 0, stream>>>(t, w_xm, ls, osc, qn, w_zs, w_zs2, w_kinv, w_A, ef, eq, w_Xw);
    k_stepC<<<8, 256, 0, stream>>>(t, w_Xw, w_taper, H, rn, y, er, out, w_xm, w_llp);
  }
  k_elbo<<<1, 64, 0, stream>>>(w_llp, w_kld, out);
  k_xfinal<<<4096, 256, 0, stream>>>(w_xm, out + 1);
}

// Round 2
// 3744.298 us; speedup vs baseline: 1.3078x; 1.3078x over previous
//
#include <hip/hip_runtime.h>
#include <hip/hip_cooperative_groups.h>

namespace cg = cooperative_groups;

#define JITF 1e-4f
#define LOG2PIF 1.8378770664093454f

// sizes: D=32, dy=32, M=128, N=128, B=8, T=48
// ws offsets (floats)
#define WZS    0          // 32*4096   zs (k-major: [d][k*128+m])
#define WZS2   131072     // 32*128
#define WKINV  135168     // 32*16384
#define WA     659456     // 32*16384  A[(n*32+d)*128+m]
#define WXW    1183744    // 32*8*128
#define WXM    1216512    // 8*32
#define WLLB   1216768    // 8
#define WKLD   1216776    // 128
// out offsets
#define OFM 1048577
#define OFV 1060865

// ---------------- Kzz build + SPD sweep inverse + KL partials + U + A ----------------
// kld: [0..31]=0.5*sum log piv (= sum log diag L), [32..63]=trace_d, [64..95]=mah_d, [96..127]=sum log|qL diag|
__global__ __launch_bounds__(512) void k_sweep(
    const float* __restrict__ ips, const float* __restrict__ ls, const float* __restrict__ osc,
    const float* __restrict__ qL, const float* __restrict__ qmu, const float* __restrict__ eu,
    float* __restrict__ zsg, float* __restrict__ zs2g,
    float* __restrict__ Kinvg, float* __restrict__ Ag, float* __restrict__ kld)
{
  __shared__ float sm[40064];
  float* A0  = sm;           // [128][129]
  float* A1  = sm + 16512;   // [128][129]
  float* zsT = sm + 33024;   // [32][128]
  float* zs2 = sm + 37120;   // 128
  float* qms = sm + 37248;   // 128
  float* piv = sm + 37376;   // 128
  float* red = sm + 37504;   // 512
  float* Uc  = sm + 38016;   // 8*128
  float* euc = sm + 39040;   // 8*128
  const int d = blockIdx.x, tid = threadIdx.x;
  const float invl = 1.0f / ls[d], oscd = osc[d];

  for (int l = tid; l < 4096; l += 512) {
    int m = l >> 5, k = l & 31;
    zsT[k*128+m] = ips[(d*128+m)*32+k] * invl;
  }
  if (tid < 128) qms[tid] = qmu[d*128+tid];
  __syncthreads();
  if (tid < 128) {
    float s = 0.f;
    for (int k = 0; k < 32; k++) { float v = zsT[k*128+tid]; s = fmaf(v, v, s); }
    zs2[tid] = s; zs2g[d*128+tid] = s;
  }
  for (int l = tid; l < 4096; l += 512) zsg[d*4096+l] = zsT[l];
  __syncthreads();
  for (int e = tid; e < 16384; e += 512) {
    int i = e >> 7, j = e & 127;
    float dot = 0.f;
    for (int k = 0; k < 32; k++) dot = fmaf(zsT[k*128+i], zsT[k*128+j], dot);
    float d2 = fmaxf(zs2[i] + zs2[j] - 2.f*dot, 0.f);
    A0[i*129+j] = oscd * expf(-0.5f*d2) + (i == j ? JITF : 0.f);
  }
  __syncthreads();

  // sweep: 128 steps, ping-pong, 1 barrier each. After all steps: cur = -Kzz^-1
  float* cur = A0; float* nxt = A1;
  for (int k = 0; k < 128; k++) {
    float p = cur[k*129+k];
    float ip = 1.0f / p;
    if (tid == 0) piv[k] = p;
    for (int e = tid; e < 16384; e += 512) {
      int i = e >> 7, j = e & 127;
      float cik = cur[i*129+k];
      float ckj = cur[k*129+j];
      float v;
      if (i == k)      v = (j == k) ? -ip : ckj*ip;
      else if (j == k) v = cik*ip;
      else             v = fmaf(-cik*ip, ckj, cur[i*129+j]);
      nxt[i*129+j] = v;
    }
    __syncthreads();
    float* tmp = cur; cur = nxt; nxt = tmp;
  }
  // negate in place -> Kinv in cur
  for (int e = tid; e < 16384; e += 512) { int i = e >> 7, j = e & 127; cur[i*129+j] = -cur[i*129+j]; }
  __syncthreads();
  for (int e = tid; e < 16384; e += 512) Kinvg[d*16384+e] = cur[(e>>7)*129 + (e&127)];
  // stage qL into the free buffer
  for (int e = tid; e < 16384; e += 512) nxt[(e>>7)*129 + (e&127)] = qL[d*16384+e];
  __syncthreads();

  // ldK
  red[tid] = (tid < 128) ? logf(piv[tid]) : 0.f;
  __syncthreads();
  for (int s = 256; s > 0; s >>= 1) { if (tid < s) red[tid] += red[tid+s]; __syncthreads(); }
  if (tid == 0) kld[d] = 0.5f * red[0];
  __syncthreads();
  // ldS
  red[tid] = (tid < 128) ? logf(fabsf(nxt[tid*129+tid])) : 0.f;
  __syncthreads();
  for (int s = 256; s > 0; s >>= 1) { if (tid < s) red[tid] += red[tid+s]; __syncthreads(); }
  if (tid == 0) kld[96+d] = red[0];
  __syncthreads();
  // mah = qmu^T Kinv qmu
  {
    float macc = 0.f;
    for (int e = tid; e < 16384; e += 512) {
      int i = e >> 7, j = e & 127;
      macc = fmaf(cur[i*129+j], qms[i]*qms[j], macc);
    }
    red[tid] = macc;
    __syncthreads();
    for (int s = 256; s > 0; s >>= 1) { if (tid < s) red[tid] += red[tid+s]; __syncthreads(); }
    if (tid == 0) kld[64+d] = red[0];
    __syncthreads();
  }
  // trace = sum_{i,k} qL[i][k] * (Kinv qL)[i][k]
  {
    float tacc = 0.f;
    for (int e = tid; e < 16384; e += 512) {
      int i = e >> 7, k2 = e & 127;
      if (k2 <= i) {
        float w = 0.f;
        for (int m = k2; m < 128; m++) w = fmaf(cur[i*129+m], nxt[m*129+k2], w);
        tacc = fmaf(w, nxt[i*129+k2], tacc);
      }
    }
    red[tid] = tacc;
    __syncthreads();
    for (int s = 256; s > 0; s >>= 1) { if (tid < s) red[tid] += red[tid+s]; __syncthreads(); }
    if (tid == 0) kld[32+d] = red[0];
    __syncthreads();
  }
  // U = qmu + qL @ eps_u ; A = Kinv @ U   (chunks of 8 n)
  for (int c = 0; c < 16; c++) {
    int n0 = c * 8;
    for (int l = tid; l < 1024; l += 512) euc[l] = eu[((n0 + (l>>7))*32 + d)*128 + (l&127)];
    __syncthreads();
    for (int e = tid; e < 1024; e += 512) {
      int nn = e >> 7, m = e & 127;
      float s = qms[m];
      for (int k2 = 0; k2 <= m; k2++) s = fmaf(nxt[m*129+k2], euc[nn*128+k2], s);
      Uc[e] = s;
    }
    __syncthreads();
    for (int e = tid; e < 1024; e += 512) {
      int nn = e >> 7, m = e & 127;
      float s = 0.f;
      for (int mm = 0; mm < 128; mm++) s = fmaf(cur[m*129+mm], Uc[nn*128+mm], s);
      Ag[((n0+nn)*32 + d)*128 + m] = s;
    }
    __syncthreads();
  }
}

// ---------------- t = 0: full per-(n,d) GP predict ----------------
__global__ __launch_bounds__(128) void k_t0gp(
    const float* __restrict__ x0, const float* __restrict__ ls, const float* __restrict__ osc,
    const float* __restrict__ qn, const float* __restrict__ zs, const float* __restrict__ zs2,
    const float* __restrict__ Kinv, const float* __restrict__ A,
    const float* __restrict__ ef, const float* __restrict__ eq, float* __restrict__ Xw)
{
  __shared__ float zssT[4096];
  __shared__ float xqs[8][33];
  __shared__ float xq2s[8];
  __shared__ float Kxzs[8][132];
  __shared__ float T1s[8][132];
  __shared__ float covs[8][9];
  __shared__ float Lc[8][9];
  __shared__ float Arow[128];
  const int n = blockIdx.x >> 5, d = blockIdx.x & 31, tid = threadIdx.x;
  const float invl = 1.0f / ls[d], oscd = osc[d];
  for (int l = tid; l < 4096; l += 128) zssT[l] = zs[d*4096 + l];
  for (int l = tid; l < 256; l += 128) {
    int b = l >> 5, k = l & 31;
    xqs[b][k] = x0[((n*32+d)*8 + b)*32 + k] * invl;
  }
  Arow[tid] = A[(n*32+d)*128 + tid];
  __syncthreads();
  if (tid < 8) {
    float s = 0.f;
#pragma unroll
    for (int k = 0; k < 32; k++) { float v = xqs[tid][k]; s = fmaf(v, v, s); }
    xq2s[tid] = s;
  }
  __syncthreads();
  {
    float z2m = zs2[d*128 + tid];
#pragma unroll
    for (int b = 0; b < 8; b++) {
      float dot = 0.f;
#pragma unroll
      for (int k = 0; k < 32; k++) dot = fmaf(xqs[b][k], zssT[k*128 + tid], dot);
      Kxzs[b][tid] = oscd * expf(-0.5f * fmaxf(xq2s[b] + z2m - 2.f*dot, 0.f));
    }
  }
  __syncthreads();
  {
    float a[8] = {0.f,0.f,0.f,0.f,0.f,0.f,0.f,0.f};
    const float* kp = Kinv + d*16384 + tid;
    for (int mm = 0; mm < 128; mm++) {
      float kv = kp[mm*128];
#pragma unroll
      for (int b = 0; b < 8; b++) a[b] = fmaf(Kxzs[b][mm], kv, a[b]);
    }
#pragma unroll
    for (int b = 0; b < 8; b++) T1s[b][tid] = a[b];
  }
  __syncthreads();
  if (tid < 64) {
    int b = tid >> 3, c = tid & 7;
    float dot = 0.f;
#pragma unroll
    for (int k = 0; k < 32; k++) dot = fmaf(xqs[b][k], xqs[c][k], dot);
    float kxx = oscd * expf(-0.5f * fmaxf(xq2s[b] + xq2s[c] - 2.f*dot, 0.f));
    float s0 = 0.f, s1 = 0.f;
    for (int m = 0; m < 128; m += 2) {
      s0 = fmaf(T1s[b][m], Kxzs[c][m], s0);
      s1 = fmaf(T1s[b][m+1], Kxzs[c][m+1], s1);
    }
    covs[b][c] = kxx - (s0+s1) + (b == c ? JITF : 0.f);
  }
  __syncthreads();
  if (tid == 0) {
    for (int a = 0; a < 8; a++) {
      float s = covs[a][a];
      for (int k = 0; k < a; k++) s -= Lc[a][k]*Lc[a][k];
      float la = sqrtf(s);
      Lc[a][a] = la;
      for (int i = a+1; i < 8; i++) {
        float s2 = covs[i][a];
        for (int k = 0; k < a; k++) s2 -= Lc[i][k]*Lc[a][k];
        Lc[i][a] = s2 / la;
      }
      for (int c = a+1; c < 8; c++) Lc[a][c] = 0.f;
    }
  }
  __syncthreads();
  if (tid < 8) {
    int b = tid;
    float m0 = 0.f, m1 = 0.f;
    for (int m = 0; m < 128; m += 2) {
      m0 = fmaf(Kxzs[b][m], Arow[m], m0);
      m1 = fmaf(Kxzs[b][m+1], Arow[m+1], m1);
    }
    float f = m0 + m1;
#pragma unroll
    for (int c = 0; c < 8; c++) f = fmaf(Lc[b][c], ef[(n*32+d)*8 + c], f);
    float X = f + eq[(b*128+n)*32 + d] * sqrtf(qn[d]);
    Xw[(d*8+b)*128 + n] = X;
  }
}

// ---------------- cooperative scan over T=48 ----------------
// blocks 0..31: d-role (GP predict, Kinv+A persistent in LDS)
// blocks 32..39: b-role (ensemble moments + Kalman via 32x32 sweep)
__global__ __launch_bounds__(256) void k_scan(
    const float* __restrict__ ls, const float* __restrict__ osc,
    const float* __restrict__ qn, const float* __restrict__ rn,
    const float* __restrict__ H, const float* __restrict__ y,
    const float* __restrict__ ef, const float* __restrict__ eq,
    const float* __restrict__ er,
    const float* __restrict__ zsg, const float* __restrict__ zs2g,
    const float* __restrict__ Kinvg, const float* __restrict__ Ag,
    float* __restrict__ Xw, float* __restrict__ xm,
    float* __restrict__ llb, const float* __restrict__ kld,
    float* __restrict__ out)
{
  cg::grid_group grid = cg::this_grid();
  __shared__ float sm[40032];
  const int blk = blockIdx.x, tid = threadIdx.x;

  if (blk < 32) {
    const int d = blk;
    float* KinvS = sm;             // [mm*128+m] 16384
    float* AS    = sm + 16384;     // [n*132+m]  16896
    float* zsT   = sm + 33280;     // 4096
    float* zs2   = sm + 37376;     // 128
    float* Kxz   = sm + 37504;     // [b*132+m] 1056
    float* T1    = sm + 38560;     // 1056
    float* xqs   = sm + 39616;     // [b*33+k] 264
    float* xq2   = sm + 39880;     // 8
    float* covB  = sm + 39888;     // 72
    float* Lc    = sm + 39960;     // 72
    const float invl = 1.0f / ls[d], oscd = osc[d], qsd = sqrtf(qn[d]);
    for (int l = tid; l < 16384; l += 256) KinvS[l] = Kinvg[d*16384 + l];
    for (int l = tid; l < 16384; l += 256) AS[(l>>7)*132 + (l&127)] = Ag[((l>>7)*32 + d)*128 + (l&127)];
    for (int l = tid; l < 4096; l += 256) zsT[l] = zsg[d*4096 + l];
    if (tid < 128) zs2[tid] = zs2g[d*128 + tid];
    grid.sync();                                   // S0: C(0) done
    for (int t = 1; t < 48; t++) {
      { int b = tid >> 5, k = tid & 31; xqs[b*33+k] = xm[b*32+k] * invl; }
      __syncthreads();
      if (tid < 8) {
        float s = 0.f;
#pragma unroll
        for (int k = 0; k < 32; k++) { float v = xqs[tid*33+k]; s = fmaf(v, v, s); }
        xq2[tid] = s;
      }
      __syncthreads();
      for (int e = tid; e < 1024; e += 256) {
        int b = e >> 7, m = e & 127;
        float dot = 0.f;
#pragma unroll
        for (int k = 0; k < 32; k++) dot = fmaf(xqs[b*33+k], zsT[k*128+m], dot);
        Kxz[b*132+m] = oscd * expf(-0.5f * fmaxf(xq2[b] + zs2[m] - 2.f*dot, 0.f));
      }
      __syncthreads();
      {
        int m = tid & 127, h = tid >> 7;
        float a0=0.f,a1=0.f,a2=0.f,a3=0.f;
        for (int mm = 0; mm < 128; mm++) {
          float kv = KinvS[mm*128 + m];
          a0 = fmaf(Kxz[(h+0)*132+mm], kv, a0);
          a1 = fmaf(Kxz[(h+2)*132+mm], kv, a1);
          a2 = fmaf(Kxz[(h+4)*132+mm], kv, a2);
          a3 = fmaf(Kxz[(h+6)*132+mm], kv, a3);
        }
        T1[(h+0)*132+m]=a0; T1[(h+2)*132+m]=a1; T1[(h+4)*132+m]=a2; T1[(h+6)*132+m]=a3;
      }
      __syncthreads();
      if (tid < 64) {
        int b = tid >> 3, c = tid & 7;
        float dot = 0.f;
#pragma unroll
        for (int k = 0; k < 32; k++) dot = fmaf(xqs[b*33+k], xqs[c*33+k], dot);
        float kxx = oscd * expf(-0.5f * fmaxf(xq2[b] + xq2[c] - 2.f*dot, 0.f));
        float s0 = 0.f, s1 = 0.f;
        for (int m = 0; m < 128; m += 2) {
          s0 = fmaf(T1[b*132+m],   Kxz[c*132+m],   s0);
          s1 = fmaf(T1[b*132+m+1], Kxz[c*132+m+1], s1);
        }
        covB[b*9+c] = kxx - (s0+s1) + (b == c ? JITF : 0.f);
      }
      __syncthreads();
      if (tid == 0) {
        for (int a = 0; a < 8; a++) {
          float s = covB[a*9+a];
          for (int k = 0; k < a; k++) s -= Lc[a*9+k]*Lc[a*9+k];
          float la = sqrtf(s);
          Lc[a*9+a] = la;
          for (int i = a+1; i < 8; i++) {
            float s2 = covB[i*9+a];
            for (int k = 0; k < a; k++) s2 -= Lc[i*9+k]*Lc[a*9+k];
            Lc[i*9+a] = s2 / la;
          }
        }
      }
      __syncthreads();
      for (int e = tid; e < 1024; e += 256) {
        int b = e & 7, n = e >> 3;
        float m0 = 0.f, m1 = 0.f;
        for (int m = 0; m < 128; m += 2) {
          m0 = fmaf(Kxz[b*132+m],   AS[n*132+m],   m0);
          m1 = fmaf(Kxz[b*132+m+1], AS[n*132+m+1], m1);
        }
        float f = m0 + m1;
        for (int c = 0; c <= b; c++) f = fmaf(Lc[b*9+c], ef[((t*128+n)*32+d)*8 + c], f);
        Xw[(d*8+b)*128 + n] = f + eq[((t*8+b)*128+n)*32 + d] * qsd;
      }
      grid.sync();                                 // AB(t) done
      grid.sync();                                 // C(t) done
    }
    grid.sync();                                   // S95
  } else {
    const int b = blk - 32;
    float* Xs     = sm;            // [n*33+dd] 4224
    float* Hs     = sm + 4224;     // [j*33+k] 1056
    float* Ps     = sm + 5280;     // 1056
    float* HPs    = sm + 6336;     // 1056
    float* Sb     = sm + 7392;     // [2][32*33] 2112
    float* Ks     = sm + 9504;     // 1056
    float* taperS = sm + 10560;    // 1024
    float* mers   = sm + 11584;    // [t*32+j] 1536
    float* Xms    = sm + 13120;    // 32
    float* resid  = sm + 13152;    // 32
    float* alph   = sm + 13184;    // 32
    float* mi     = sm + 13216;    // 32
    float* pivS   = sm + 13248;    // 32
    float* redb   = sm + 13280;    // [8][33] 264
    float llacc = 0.f;
    for (int l = tid; l < 1024; l += 256) {
      int i = l >> 5, j = l & 31;
      int ad = i - j; if (ad < 0) ad = -ad;
      int dist = (ad < 32 - ad) ? ad : (32 - ad);
      double z = (double)dist / 5.0;
      double z2 = z*z, z3 = z2*z, z4 = z3*z, z5 = z4*z;
      double gval;
      if (z < 1.0) gval = 1.0 - (5.0/3.0)*z2 + (5.0/8.0)*z3 + 0.5*z4 - 0.25*z5;
      else if (z < 2.0) gval = 4.0 - 5.0*z + (5.0/3.0)*z2 + (5.0/8.0)*z3 - 0.5*z4 + (1.0/12.0)*z5 - 2.0/(3.0*z);
      else gval = 0.0;
      taperS[l] = (float)gval;
      Hs[i*33+j] = H[l];
    }
    __syncthreads();
    // mers[t][j] = mean_n er[t,b,n,j]
    for (int t = 0; t < 48; t++) {
      int j = tid & 31, g2 = tid >> 5;
      float s = 0.f;
      for (int nn = 0; nn < 16; nn++) s += er[((t*8+b)*128 + (g2*16+nn))*32 + j];
      redb[g2*33+j] = s;
      __syncthreads();
      if (tid < 32) {
        float s2 = 0.f;
        for (int g3 = 0; g3 < 8; g3++) s2 += redb[g3*33+tid];
        mers[t*32+tid] = s2 * (1.0f/128.0f);
      }
      __syncthreads();
    }

    auto Cphase = [&](int t) {
      for (int l = tid; l < 4096; l += 256) {
        int dd = l >> 7, n = l & 127;
        Xs[n*33+dd] = Xw[(dd*8+b)*128 + n];
      }
      __syncthreads();
      if (tid < 32) {
        float s = 0.f;
        for (int n = 0; n < 128; n++) s += Xs[n*33+tid];
        Xms[tid] = s * (1.0f/128.0f);
      }
      __syncthreads();
      for (int e = tid; e < 1024; e += 256) {
        int i = e >> 5, j2 = e & 31;
        float s0 = 0.f, s1 = 0.f;
        for (int n = 0; n < 128; n += 2) {
          s0 = fmaf(Xs[n*33+i],     Xs[n*33+j2],     s0);
          s1 = fmaf(Xs[(n+1)*33+i], Xs[(n+1)*33+j2], s1);
        }
        Ps[i*33+j2] = taperS[e] * ((s0+s1) - 128.f*Xms[i]*Xms[j2]) * (1.0f/127.0f);
      }
      __syncthreads();
      for (int e = tid; e < 1024; e += 256) {
        int j2 = e >> 5, i = e & 31;
        float s = 0.f;
#pragma unroll
        for (int k = 0; k < 32; k++) s = fmaf(Hs[j2*33+k], Ps[k*33+i], s);
        HPs[j2*33+i] = s;
      }
      __syncthreads();
      for (int e = tid; e < 1024; e += 256) {
        int j2 = e >> 5, l2 = e & 31;
        float s = 0.f;
#pragma unroll
        for (int k = 0; k < 32; k++) s = fmaf(HPs[j2*33+k], Hs[l2*33+k], s);
        Sb[j2*33+l2] = s + (j2 == l2 ? rn[j2] : 0.f);
      }
      __syncthreads();
      // sweep 32x32 -> Sb[0] = -S^-1, pivots in pivS
      int cur = 0;
      for (int k = 0; k < 32; k++) {
        float p = Sb[cur*1056 + k*33 + k];
        float ip = 1.0f / p;
        if (tid == 0) pivS[k] = p;
        for (int e = tid; e < 1024; e += 256) {
          int i = e >> 5, j2 = e & 31;
          float cik = Sb[cur*1056 + i*33 + k];
          float ckj = Sb[cur*1056 + k*33 + j2];
          float v;
          if (i == k)       v = (j2 == k) ? -ip : ckj*ip;
          else if (j2 == k) v = cik*ip;
          else              v = fmaf(-cik*ip, ckj, Sb[cur*1056 + i*33 + j2]);
          Sb[(cur^1)*1056 + i*33 + j2] = v;
        }
        __syncthreads();
        cur ^= 1;
      }
      if (tid < 32) {
        float s = 0.f;
#pragma unroll
        for (int i = 0; i < 32; i++) s = fmaf(Hs[tid*33+i], Xms[i], s);
        resid[tid] = y[(b*48+t)*32 + tid] - s;
      }
      __syncthreads();
      if (tid < 32) {
        float s = 0.f;
#pragma unroll
        for (int k = 0; k < 32; k++) s = fmaf(-Sb[tid*33+k], resid[k], s);
        alph[tid] = s;
        mi[tid] = resid[tid] + mers[t*32+tid] * sqrtf(rn[tid]);
      }
      __syncthreads();
      for (int e = tid; e < 1024; e += 256) {
        int i = e >> 5, j2 = e & 31;
        float s = 0.f;
#pragma unroll
        for (int k = 0; k < 32; k++) s = fmaf(HPs[k*33+i], -Sb[k*33+j2], s);
        Ks[i*33+j2] = s;
      }
      if (tid == 0) {
        float quad = 0.f, ld = 0.f;
        for (int k = 0; k < 32; k++) { quad = fmaf(resid[k], alph[k], quad); ld += logf(pivS[k]); }
        llacc += -0.5f * (32.0f*LOG2PIF + ld + quad);
      }
      __syncthreads();
      if (tid < 32) {
        int i = tid;
        float xs = 0.f, fv = 0.f;
#pragma unroll
        for (int j2 = 0; j2 < 32; j2++) {
          xs = fmaf(Ks[i*33+j2], mi[j2], xs);
          fv = fmaf(Ks[i*33+j2], HPs[j2*33+i], fv);
        }
        float xmp = Xms[i] + xs;
        out[OFM + (b*48+t)*32 + i] = xmp;
        out[OFV + (b*48+t)*32 + i] = Ps[i*33+i] - fv;
        xm[b*32+i] = xmp;
      }
      __syncthreads();
    };

    Cphase(0);
    grid.sync();                                   // S0
    for (int t = 1; t < 48; t++) {
      grid.sync();                                 // AB(t) done
      Cphase(t);
      grid.sync();                                 // C(t) done
    }
    if (tid == 0) llb[b] = llacc;
    grid.sync();                                   // S95
  }

  // epilogue: x_final broadcast + elbo
  for (int idx = blk*256 + tid; idx < 1048576; idx += 40*256)
    out[1 + idx] = xm[((idx >> 5) & 7)*32 + (idx & 31)];
  if (blk == 0 && tid == 0) {
    double ll = 0.0;
    for (int i = 0; i < 8; i++) ll += (double)llb[i];
    double ldK = 0.0, tr = 0.0, mah = 0.0, ldS = 0.0;
    for (int d2 = 0; d2 < 32; d2++) {
      ldK += (double)kld[d2];
      tr  += (double)kld[32+d2];
      mah += (double)kld[64+d2];
      ldS += (double)kld[96+d2];
    }
    double klv = 0.5*(tr + mah - 4096.0 + 2.0*ldK - 2.0*ldS);
    out[0] = (float)(ll - klv/100000.0);
  }
}

extern "C" void kernel_launch(void* const* d_in, const int* in_sizes, int n_in,
                              void* d_out, int out_size, void* d_ws, size_t ws_size,
                              hipStream_t stream) {
  const float* ips = (const float*)d_in[0];
  const float* H   = (const float*)d_in[1];
  const float* ls  = (const float*)d_in[2];
  const float* osc = (const float*)d_in[3];
  const float* qmu = (const float*)d_in[4];
  const float* qL  = (const float*)d_in[5];
  const float* qn  = (const float*)d_in[6];
  const float* rn  = (const float*)d_in[7];
  const float* x0  = (const float*)d_in[8];
  const float* y   = (const float*)d_in[9];
  const float* eu  = (const float*)d_in[10];
  const float* ef  = (const float*)d_in[11];
  const float* eq  = (const float*)d_in[12];
  const float* er  = (const float*)d_in[13];
  float* out = (float*)d_out;
  float* ws  = (float*)d_ws;

  float* w_zs   = ws + WZS;
  float* w_zs2  = ws + WZS2;
  float* w_kinv = ws + WKINV;
  float* w_A    = ws + WA;
  float* w_Xw   = ws + WXW;
  float* w_xm   = ws + WXM;
  float* w_llb  = ws + WLLB;
  float* w_kld  = ws + WKLD;

  k_sweep<<<32, 512, 0, stream>>>(ips, ls, osc, qL, qmu, eu, w_zs, w_zs2, w_kinv, w_A, w_kld);
  k_t0gp<<<4096, 128, 0, stream>>>(x0, ls, osc, qn, w_zs, w_zs2, w_kinv, w_A, ef, eq, w_Xw);
  void* args[] = { (void*)&ls, (void*)&osc, (void*)&qn, (void*)&rn, (void*)&H, (void*)&y,
                   (void*)&ef, (void*)&eq, (void*)&er, (void*)&w_zs, (void*)&w_zs2,
                   (void*)&w_kinv, (void*)&w_A, (void*)&w_Xw, (void*)&w_xm, (void*)&w_llb,
                   (void*)&w_kld, (void*)&out };
  hipLaunchCooperativeKernel((void*)k_scan, dim3(40), dim3(256), args, 0, stream);
}